// Round 16
// baseline (274.022 us; speedup 1.0000x reference)
//
#include <hip/hip_runtime.h>

#define B_    128
#define L_    512
#define H_    256
#define TGB_  128
#define S_    1023
#define BL_   (B_ * L_)     // 65536
#define SIXH  1536
#define FOURH 1024

typedef __bf16 bf16_t;
typedef bf16_t bf16x8 __attribute__((ext_vector_type(8)));
typedef float  f32x4  __attribute__((ext_vector_type(4)));
typedef unsigned short u16x4 __attribute__((ext_vector_type(4)));

template<int P> struct IC { static constexpr int v = P; };

__device__ __forceinline__ unsigned short f2bf(float f) {
    union { float f; unsigned u; } v; v.f = f;
    unsigned u = v.u;
    unsigned r = u + 0x7FFFu + ((u >> 16) & 1u);   // round-to-nearest-even
    return (unsigned short)(r >> 16);
}

__device__ __forceinline__ void gload_lds16(const void* g, void* l) {
    __builtin_amdgcn_global_load_lds(
        (__attribute__((address_space(1))) void*)(void*)(g),
        (__attribute__((address_space(3))) void*)(l), 16, 0, 0);
}

// ---------------------------------------------------------------------------
// K0: transpose + f32->bf16 convert:  in (R x C) f32  ->  out (C x R) bf16
// ---------------------------------------------------------------------------
__global__ __launch_bounds__(256) void transpose_bf16_kernel(
    const float* __restrict__ in, unsigned short* __restrict__ out,
    int R, int C)
{
    __shared__ float tile[32][33];
    int rb = blockIdx.x * 32, cb = blockIdx.y * 32;
    int tx = threadIdx.x & 31, ty = threadIdx.x >> 5;   // 32 x 8
    #pragma unroll
    for (int d = 0; d < 32; d += 8)
        tile[ty + d][tx] = in[(size_t)(rb + ty + d) * C + cb + tx];
    __syncthreads();
    #pragma unroll
    for (int d = 0; d < 32; d += 8)
        out[(size_t)(cb + ty + d) * R + rb + tx] = f2bf(tile[tx][ty + d]);
}

// ---------------------------------------------------------------------------
// K1: compacted gather + LayerNorm. One wave per valid event j.
// ---------------------------------------------------------------------------
__global__ __launch_bounds__(256) void embed_ln_kernel(
    const int* __restrict__ tok,  const int* __restrict__ ptok,
    const int* __restrict__ atok, const int* __restrict__ actok,
    const int* __restrict__ tgap, const int* __restrict__ gid,
    const float* __restrict__ ttab, const float* __restrict__ titab,
    const float* __restrict__ gtab, const float* __restrict__ gamma,
    const float* __restrict__ beta, const int* __restrict__ row_id,
    const int* __restrict__ Vdev, unsigned short* __restrict__ xln)
{
    int j = blockIdx.x * 4 + (threadIdx.x >> 6);
    if (j >= *Vdev) return;
    int l = threadIdx.x & 63;
    int rid = row_id[j];
    int i0 = tok[rid], i1 = ptok[rid], i2 = atok[rid], i3 = actok[rid];
    int i4 = tgap[rid]; i4 = i4 < 0 ? 0 : (i4 > TGB_ ? TGB_ : i4);
    int i5 = gid[rid];
    f32x4 v[6];
    v[0] = *(const f32x4*)(ttab  + (size_t)i0 * H_ + l * 4);
    v[1] = *(const f32x4*)(ttab  + (size_t)i1 * H_ + l * 4);
    v[2] = *(const f32x4*)(ttab  + (size_t)i2 * H_ + l * 4);
    v[3] = *(const f32x4*)(ttab  + (size_t)i3 * H_ + l * 4);
    v[4] = *(const f32x4*)(titab + (size_t)i4 * H_ + l * 4);
    v[5] = *(const f32x4*)(gtab  + (size_t)i5 * H_ + l * 4);
    float s = 0.0f, sq = 0.0f;
    #pragma unroll
    for (int k = 0; k < 6; ++k)
        #pragma unroll
        for (int c = 0; c < 4; ++c) { float f = v[k][c]; s += f; sq += f * f; }
    #pragma unroll
    for (int off = 32; off > 0; off >>= 1) {
        s  += __shfl_xor(s,  off);
        sq += __shfl_xor(sq, off);
    }
    float mean = s * (1.0f / 1536.0f);
    float var  = sq * (1.0f / 1536.0f) - mean * mean;
    float rstd = rsqrtf(var + 1e-5f);
    unsigned short* orow = xln + (size_t)j * SIXH;
    #pragma unroll
    for (int k = 0; k < 6; ++k) {
        f32x4 g = *(const f32x4*)(gamma + k * H_ + l * 4);
        f32x4 b = *(const f32x4*)(beta  + k * H_ + l * 4);
        u16x4 o;
        #pragma unroll
        for (int c = 0; c < 4; ++c)
            o[c] = f2bf((v[k][c] - mean) * rstd * g[c] + b[c]);
        *(u16x4*)(orow + k * H_ + l * 4) = o;
    }
}

// ---------------------------------------------------------------------------
// K2a: GEMM1 = r3-verified ring-of-3 deep pipeline, BM=256 x BN=128, BK=64,
// 512 thr = 8 waves (4m x 2n), counted s_waitcnt vmcnt(6) (never drains
// mid-loop -- loads get ~2 K-tiles to cover HBM latency), 144 KiB LDS,
// MFMA clusters interleaved 1:1 with staging issues. Dynamic V via
// early-exit beyond nact + m204 bijective XCD swizzle (r9-verified).
// silu epilogue -> bf16 C (N = NTN*128).
// ---------------------------------------------------------------------------
template<int N, int K, int NTN>
__global__ __launch_bounds__(512, 2) void gemm8_kernel(
    const unsigned short* __restrict__ A,
    const unsigned short* __restrict__ Bt,
    const float* __restrict__ bias,
    unsigned short* __restrict__ C,
    const int* __restrict__ Vdev)
{
    constexpr int NT = K / 64;                // K-tiles
    constexpr int ASLOT = 256 * 64;
    constexpr int BSLOT = 128 * 64;
    extern __shared__ __align__(16) unsigned short lds[];
    unsigned short* sA = lds;
    unsigned short* sB = lds + 3 * ASLOT;

    const int V = *Vdev;
    const int nact = ((V + 255) >> 8) * NTN;
    const int bid = blockIdx.x;
    if (bid >= nact) return;
    const int qd = nact >> 3, rd = nact & 7, x = bid & 7, o = bid >> 3;
    const int wid = (x < rd ? x * (qd + 1) : rd * (qd + 1) + (x - rd) * qd) + o;
    const int m0 = (wid / NTN) * 256;
    const int n0 = (wid % NTN) * 128;

    int t = threadIdx.x;
    int w = t >> 6, l = t & 63;
    int srow = t >> 3;
    int scg  = (t & 7) ^ (srow & 7);
    const unsigned short* Ag = A  + (size_t)(m0 + srow) * K + scg * 8;
    const unsigned short* Bg = Bt + (size_t)(n0 + srow) * K + scg * 8;
    unsigned short* stA = sA + w * 512;
    unsigned short* stB = sB + w * 512;

    int r16 = l & 15, q = l >> 4;
    int wm = w >> 1, wn = w & 1;             // 4m x 2n
    int xr = r16 & 7;
    const int aoff = (wm * 64 + r16) * 64;
    const int boff = (wn * 64 + r16) * 64;
    const int c0 = ((0 + q) ^ xr) * 8;
    const int c1 = ((4 + q) ^ xr) * 8;

    f32x4 acc[4][4];
    #pragma unroll
    for (int i = 0; i < 4; ++i)
        #pragma unroll
        for (int j = 0; j < 4; ++j) acc[i][j] = (f32x4)0.0f;

    // prologue: kt=0 -> slot0, kt=1 -> slot1
    #pragma unroll
    for (int j = 0; j < 4; ++j) gload_lds16(Ag + (size_t)j * 64 * K, stA + j * 4096);
    #pragma unroll
    for (int j = 0; j < 2; ++j) gload_lds16(Bg + (size_t)j * 64 * K, stB + j * 4096);
    #pragma unroll
    for (int j = 0; j < 4; ++j) gload_lds16(Ag + (size_t)j * 64 * K + 64, stA + ASLOT + j * 4096);
    #pragma unroll
    for (int j = 0; j < 2; ++j) gload_lds16(Bg + (size_t)j * 64 * K + 64, stB + BSLOT + j * 4096);
    asm volatile("s_waitcnt vmcnt(6)\ns_barrier" ::: "memory");

    int s = 0;
    for (int kt = 0; kt < NT; ++kt) {
        const unsigned short* sAs = sA + s * ASLOT;
        const unsigned short* sBs = sB + s * BSLOT;
        int spf = s + 2; if (spf >= 3) spf -= 3;
        const size_t gofs = (size_t)(kt + 2) * 64;
        unsigned short* pA = stA + spf * ASLOT;
        unsigned short* pB = stB + spf * BSLOT;

        bf16x8 af[4][2];
        #pragma unroll
        for (int mi = 0; mi < 4; ++mi) {
            af[mi][0] = *(const bf16x8*)(sAs + aoff + mi * 1024 + c0);
            af[mi][1] = *(const bf16x8*)(sAs + aoff + mi * 1024 + c1);
        }
        #pragma unroll
        for (int ni = 0; ni < 4; ++ni) {
            bf16x8 b0 = *(const bf16x8*)(sBs + boff + ni * 1024 + c0);
            bf16x8 b1 = *(const bf16x8*)(sBs + boff + ni * 1024 + c1);
            if (kt + 2 < NT) {
                if (ni == 0) {
                    gload_lds16(Ag + gofs,                    pA);
                    gload_lds16(Ag + (size_t) 64 * K + gofs,  pA + 4096);
                } else if (ni == 1) {
                    gload_lds16(Ag + (size_t)128 * K + gofs,  pA + 8192);
                    gload_lds16(Ag + (size_t)192 * K + gofs,  pA + 12288);
                } else if (ni == 2) {
                    gload_lds16(Bg + gofs,                    pB);
                } else {
                    gload_lds16(Bg + (size_t) 64 * K + gofs,  pB + 4096);
                }
            }
            __builtin_amdgcn_s_setprio(1);
            #pragma unroll
            for (int mi = 0; mi < 4; ++mi) {
                acc[mi][ni] = __builtin_amdgcn_mfma_f32_16x16x32_bf16(af[mi][0], b0, acc[mi][ni], 0, 0, 0);
                acc[mi][ni] = __builtin_amdgcn_mfma_f32_16x16x32_bf16(af[mi][1], b1, acc[mi][ni], 0, 0, 0);
            }
            __builtin_amdgcn_s_setprio(0);
        }
        if (kt + 2 < NT)      asm volatile("s_waitcnt vmcnt(6)\ns_barrier" ::: "memory");
        else if (kt + 1 < NT) asm volatile("s_waitcnt vmcnt(0)\ns_barrier" ::: "memory");
        s = (s == 2) ? 0 : s + 1;
    }

    // silu epilogue -> bf16 C
    #pragma unroll
    for (int mi = 0; mi < 4; ++mi) {
        #pragma unroll
        for (int ni = 0; ni < 4; ++ni) {
            int col = n0 + wn * 64 + ni * 16 + r16;
            float bv = bias[col];
            #pragma unroll
            for (int j = 0; j < 4; ++j) {
                int row = m0 + wm * 64 + mi * 16 + q * 4 + j;
                float v = acc[mi][ni][j] + bv;
                v = v / (1.0f + __expf(-v));   // silu
                C[(size_t)row * N + col] = f2bf(v);
            }
        }
    }
}

// ---------------------------------------------------------------------------
// K2b: GEMM2 = 8-phase 128x128 (r10 inner loop verbatim; 0 conflicts),
// fused scatter epilogue -> out f32. Grid 1024, XCD-preserving stride.
// ---------------------------------------------------------------------------
template<int K, int NTN>
__global__ __launch_bounds__(256, 2) void gemm128s_kernel(
    const unsigned short* __restrict__ A,
    const unsigned short* __restrict__ Bt,
    const float* __restrict__ bias,
    const int* __restrict__ outslot,
    const int* __restrict__ posC,
    const float* __restrict__ ptab,
    float* __restrict__ outF,
    const int* __restrict__ Vdev)
{
    constexpr int NT = K / 64;        // K-tiles
    constexpr int IT = NT / 2;        // 2 K-tiles per iteration
    extern __shared__ __align__(16) unsigned short lds[];   // 32768 shorts

    const int V = *Vdev;
    const int nact = ((V + 127) >> 7) * NTN;
    const int q = nact >> 3, r = nact & 7;

    const int t = threadIdx.x;
    const int w = t >> 6, l = t & 63;
    const int wm = w >> 1, wn = w & 1;
    const int r16 = l & 15, ql = l >> 4;
    const int sg = (t & 3) ^ ((t >> 3) & 3);
    unsigned short* ldsb = lds + w * 512;              // wave-uniform dest base
    const int fr = (ql ^ ((r16 >> 1) & 3)) * 8;

    const unsigned short* la0 = lds + (wm * 64 + r16) * 32 + fr;
    const unsigned short* la1 = la0 + 16384;
    const unsigned short* lb0 = lds + 8192 + (wn * 64 + r16) * 32 + fr;
    const unsigned short* lb1 = lb0 + 16384;

    for (int bidv = blockIdx.x; bidv < nact; bidv += (int)gridDim.x) {
        const int x = bidv & 7, o = bidv >> 3;
        const int wid = (x < r ? x * (q + 1) : r * (q + 1) + (x - r) * q) + o;
        const int mt  = wid / NTN;
        const int m0  = mt * 128;
        const int n0  = (wid - mt * NTN) * 128;

        const unsigned short* As0 = A  + (size_t)(m0 + (t >> 2)) * K + sg * 8;
        const unsigned short* As1 = As0 + (size_t)64 * K;
        const unsigned short* Bs0 = Bt + (size_t)(n0 + (t >> 2)) * K + sg * 8;
        const unsigned short* Bs1 = Bs0 + (size_t)64 * K;

        f32x4 acc[4][4];
        #pragma unroll
        for (int i = 0; i < 4; ++i)
            #pragma unroll
            for (int j = 0; j < 4; ++j) acc[i][j] = (f32x4)0.0f;

        auto ST2 = [&](const unsigned short* s0, const unsigned short* s1,
                       int dofs, int gofs) {
            gload_lds16(s0 + gofs, ldsb + dofs);
            gload_lds16(s1 + gofs, ldsb + dofs + 2048);
        };

        if (bidv != (int)blockIdx.x) __syncthreads();   // LDS WAR guard

        ST2(As0, As1, 0,     0);
        ST2(Bs0, Bs1, 8192,  0);
        ST2(As0, As1, 4096,  32);
        ST2(Bs0, Bs1, 12288, 32);
        ST2(As0, As1, 16384, 64);
        ST2(Bs0, Bs1, 24576, 64);
        asm volatile("s_waitcnt vmcnt(4)\ns_barrier" ::: "memory");

        bf16x8 bq[4];

        auto phase = [&](auto pc, bool last) {
            constexpr int P   = decltype(pc)::v;
            constexpr int BUF = P >> 2;
            constexpr int KK  = (P & 3) >> 1;
            constexpr int MH  = P & 1;
            const unsigned short* ab = (BUF ? la1 : la0) + KK * 4096 + MH * 1024;
            bf16x8 aq[2];
            if constexpr (MH == 0) {
                const unsigned short* bb = (BUF ? lb1 : lb0) + KK * 4096;
                bq[0] = *(const bf16x8*)(bb);
                bq[1] = *(const bf16x8*)(bb + 512);
                bq[2] = *(const bf16x8*)(bb + 1024);
                bq[3] = *(const bf16x8*)(bb + 1536);
            }
            aq[0] = *(const bf16x8*)(ab);
            aq[1] = *(const bf16x8*)(ab + 512);
            if constexpr (P == 0)      {            ST2(As0, As1, 20480, 96);  }
            else if constexpr (P == 1) {            ST2(Bs0, Bs1, 28672, 96);  }
            else if constexpr (P == 2) { if (!last) ST2(As0, As1, 0,     128); }
            else if constexpr (P == 3) { if (!last) ST2(Bs0, Bs1, 8192,  128); }
            else if constexpr (P == 4) { if (!last) ST2(As0, As1, 4096,  160); }
            else if constexpr (P == 5) { if (!last) ST2(Bs0, Bs1, 12288, 160); }
            else if constexpr (P == 6) { if (!last) ST2(As0, As1, 16384, 192); }
            else                       { if (!last) ST2(Bs0, Bs1, 24576, 192); }
            asm volatile("s_barrier" ::: "memory");
            __builtin_amdgcn_s_setprio(1);
            #pragma unroll
            for (int mm = 0; mm < 2; ++mm)
                #pragma unroll
                for (int nn = 0; nn < 4; ++nn)
                    acc[MH * 2 + mm][nn] = __builtin_amdgcn_mfma_f32_16x16x32_bf16(
                        aq[mm], bq[nn], acc[MH * 2 + mm][nn], 0, 0, 0);
            __builtin_amdgcn_s_setprio(0);
            if constexpr (P == 3) {
                if (last) asm volatile("s_waitcnt vmcnt(0)\ns_barrier" ::: "memory");
                else      asm volatile("s_waitcnt vmcnt(4)\ns_barrier" ::: "memory");
            } else if constexpr (P == 7) {
                if (!last) asm volatile("s_waitcnt vmcnt(4)\ns_barrier" ::: "memory");
            } else {
                asm volatile("s_barrier" ::: "memory");
            }
        };

        for (int it = 0; it < IT; ++it) {
            const bool last = (it == IT - 1);
            phase(IC<0>{}, last);
            phase(IC<1>{}, last);
            phase(IC<2>{}, last);
            phase(IC<3>{}, last);
            phase(IC<4>{}, last);
            phase(IC<5>{}, last);
            phase(IC<6>{}, last);
            phase(IC<7>{}, last);
            As0 += 128; As1 += 128; Bs0 += 128; Bs1 += 128;
        }

        // fused scatter: compact row -> out slot, + bias + pos_table
        #pragma unroll
        for (int mi = 0; mi < 4; ++mi) {
            #pragma unroll
            for (int j = 0; j < 4; ++j) {
                int row = m0 + wm * 64 + mi * 16 + ql * 4 + j;
                int slot = outslot[row];
                if (slot >= 0) {
                    float* orow = outF + (size_t)slot * H_;
                    const float* prow = ptab + (size_t)posC[row] * H_;
                    #pragma unroll
                    for (int ni = 0; ni < 4; ++ni) {
                        int col = n0 + wn * 64 + ni * 16 + r16;
                        orow[col] = acc[mi][ni][j] + bias[col] + prow[col];
                    }
                }
            }
        }
    }
}

// ---------------------------------------------------------------------------
// K3: per-batch boundary + cumsum + inverse map + compact maps.
// ---------------------------------------------------------------------------
__global__ __launch_bounds__(512) void scan_scatter_kernel(
    const int* __restrict__ gid, const int* __restrict__ lengths,
    int* __restrict__ idx_map, int* __restrict__ shiftb,
    int* __restrict__ row_id, int* __restrict__ outslot,
    int* __restrict__ posC, int* __restrict__ Vdev)
{
    int b = blockIdx.x, i = threadIdx.x;
    __shared__ int slen[128];
    __shared__ int sres[2];
    if (i < 128) slen[i] = lengths[i];
    __syncthreads();
    if (i < 64) {
        int vpart = (i < b ? slen[i] : 0) + (i + 64 < b ? slen[i + 64] : 0);
        int vall  = slen[i] + slen[i + 64];
        #pragma unroll
        for (int off = 32; off > 0; off >>= 1) {
            vpart += __shfl_xor(vpart, off);
            vall  += __shfl_xor(vall,  off);
        }
        if (i == 0) { sres[0] = vpart; sres[1] = vall; }
    }
    int len = lengths[b];
    int g  = gid[b * L_ + i];
    int gn = (i < L_ - 1) ? gid[b * L_ + i + 1] : g;
    int bnd = (i < len - 1 && g != gn) ? 1 : 0;
    __shared__ int sc[512];
    sc[i] = bnd;
    __syncthreads();
    for (int off = 1; off < 512; off <<= 1) {
        int v = (i >= off) ? sc[i - off] : 0;
        __syncthreads();
        sc[i] += v;
        __syncthreads();
    }
    int incl  = sc[i];
    int total = sc[511];
    int ex = incl - bnd;
    int M = len + total;
    int shift = S_ - M;          // always >= 0
    int pb = sres[0], V = sres[1];
    for (int s = i; s < S_; s += 512) idx_map[b * S_ + s] = -1;
    __syncthreads();
    if (i < len) {
        int p = shift + i + ex;
        idx_map[b * S_ + p] = i;
        if (bnd) idx_map[b * S_ + p + 1] = -2;
        int j = pb + i;
        row_id[j]  = b * L_ + i;
        outslot[j] = b * S_ + p;
        posC[j]    = p;
    }
    if (i == 0) shiftb[b] = shift;
    if (b == B_ - 1) {
        if (i == 0) *Vdev = V;
        if (i < 256) outslot[V + i] = -1;
    }
}

// ---------------------------------------------------------------------------
// K4: fill non-event slots: zeros (s<shift), sep slots, and the mask plane.
// ---------------------------------------------------------------------------
__global__ __launch_bounds__(256) void fill_kernel(
    const int* __restrict__ idx_map, const int* __restrict__ shiftb,
    const float* __restrict__ ptab, const float* __restrict__ sep,
    float* __restrict__ out)
{
    int b = blockIdx.y;
    int s = blockIdx.x * 4 + (threadIdx.x >> 6);
    if (s >= S_) return;
    int h = (threadIdx.x & 63) * 4;
    int shift = shiftb[b];
    float* orow = out + ((size_t)b * S_ + s) * H_;
    if (s < shift) {
        *(f32x4*)(orow + h) = (f32x4)0.0f;
    } else {
        int idx = idx_map[b * S_ + s];
        if (idx == -2) {
            f32x4 pv = *(const f32x4*)(ptab + (size_t)s * H_ + h);
            f32x4 sv = *(const f32x4*)(sep + h);
            *(f32x4*)(orow + h) = pv + sv;
        }
    }
    if ((threadIdx.x & 63) == 0)
        out[(size_t)B_ * S_ * H_ + (size_t)b * S_ + s] = (s >= shift) ? 1.0f : 0.0f;
}

// ---------------------------------------------------------------------------
extern "C" void kernel_launch(void* const* d_in, const int* in_sizes, int n_in,
                              void* d_out, int out_size, void* d_ws, size_t ws_size,
                              hipStream_t stream)
{
    const int*   tok   = (const int*)d_in[0];
    const int*   ptok  = (const int*)d_in[1];
    const int*   atok  = (const int*)d_in[2];
    const int*   actok = (const int*)d_in[3];
    const int*   tgap  = (const int*)d_in[4];
    const int*   gid   = (const int*)d_in[5];
    const int*   lens  = (const int*)d_in[6];
    const float* ttab  = (const float*)d_in[7];
    const float* titab = (const float*)d_in[8];
    const float* gtab  = (const float*)d_in[9];
    const float* post  = (const float*)d_in[10];
    const float* sep   = (const float*)d_in[11];
    const float* gamma = (const float*)d_in[12];
    const float* beta  = (const float*)d_in[13];
    const float* W1    = (const float*)d_in[14];
    const float* b1    = (const float*)d_in[15];
    const float* W2    = (const float*)d_in[16];
    const float* b2    = (const float*)d_in[17];

    unsigned short* xln  = (unsigned short*)d_ws;                 // BL*1536 bf16
    unsigned short* hbuf = xln  + (size_t)BL_ * SIXH;             // BL*1024 bf16
    unsigned short* W1T  = hbuf + (size_t)BL_ * FOURH;            // 1024*1536 bf16
    unsigned short* W2T  = W1T  + (size_t)FOURH * SIXH;           // 256*1024 bf16
    int* idx_map = (int*)(W2T + (size_t)H_ * FOURH);              // B*S int
    int* shiftb  = idx_map + B_ * S_;                             // B
    int* Vdev    = shiftb + B_;                                   // 1 (+pad)
    int* row_id  = Vdev + 4;                                      // BL
    int* outslot = row_id + BL_;                                  // BL+256
    int* posC    = outslot + BL_ + 256;                           // BL
    float* out   = (float*)d_out;

    constexpr int LDS1 = 3 * (256 * 64 + 128 * 64) * 2;           // 147456
    constexpr int LDS2 = 2 * 16384 * 2;                           // 65536
    (void)hipFuncSetAttribute((const void*)&gemm8_kernel<FOURH, SIXH, 8>,
                              hipFuncAttributeMaxDynamicSharedMemorySize, LDS1);
    (void)hipFuncSetAttribute((const void*)&gemm128s_kernel<FOURH, 2>,
                              hipFuncAttributeMaxDynamicSharedMemorySize, LDS2);

    // weight transposes (independent)
    transpose_bf16_kernel<<<dim3(SIXH / 32, FOURH / 32), 256, 0, stream>>>(W1, W1T, SIXH, FOURH);
    transpose_bf16_kernel<<<dim3(FOURH / 32, H_ / 32),   256, 0, stream>>>(W2, W2T, FOURH, H_);

    // scan + prefix + compact maps + V + pad
    scan_scatter_kernel<<<B_, 512, 0, stream>>>(gid, lens, idx_map, shiftb,
                                                row_id, outslot, posC, Vdev);

    // compacted embed + layernorm
    embed_ln_kernel<<<BL_ / 4, 256, 0, stream>>>(tok, ptok, atok, actok, tgap, gid,
                                                 ttab, titab, gtab, gamma, beta,
                                                 row_id, Vdev, xln);

    // GEMM1: ring-3 deep pipeline (early-exit beyond nact; max nact = 2048)
    gemm8_kernel<FOURH, SIXH, 8><<<2048, 512, LDS1, stream>>>(xln, W1T, b1, hbuf, Vdev);
    // GEMM2: 128^2 8-phase + fused scatter (grid 1024, XCD-preserving stride)
    gemm128s_kernel<FOURH, 2><<<1024, 256, LDS2, stream>>>(
        hbuf, W2T, b2, outslot, posC, post, out, Vdev);

    // fill zeros / sep slots / mask plane
    fill_kernel<<<dim3((S_ + 3) / 4, B_), 256, 0, stream>>>(idx_map, shiftb, post, sep, out);
}

// Round 17
// 266.025 us; speedup vs baseline: 1.0301x; 1.0301x over previous
//
#include <hip/hip_runtime.h>

#define B_    128
#define L_    512
#define H_    256
#define TGB_  128
#define S_    1023
#define BL_   (B_ * L_)     // 65536
#define SIXH  1536
#define FOURH 1024

typedef __bf16 bf16_t;
typedef bf16_t bf16x8 __attribute__((ext_vector_type(8)));
typedef float  f32x4  __attribute__((ext_vector_type(4)));
typedef unsigned short u16x4 __attribute__((ext_vector_type(4)));

template<int P> struct IC { static constexpr int v = P; };

__device__ __forceinline__ unsigned short f2bf(float f) {
    union { float f; unsigned u; } v; v.f = f;
    unsigned u = v.u;
    unsigned r = u + 0x7FFFu + ((u >> 16) & 1u);   // round-to-nearest-even
    return (unsigned short)(r >> 16);
}

__device__ __forceinline__ void gload_lds16(const void* g, void* l) {
    __builtin_amdgcn_global_load_lds(
        (__attribute__((address_space(1))) void*)(void*)(g),
        (__attribute__((address_space(3))) void*)(l), 16, 0, 0);
}

// ---------------------------------------------------------------------------
// K0: transpose + f32->bf16 convert:  in (R x C) f32  ->  out (C x R) bf16
// ---------------------------------------------------------------------------
__global__ __launch_bounds__(256) void transpose_bf16_kernel(
    const float* __restrict__ in, unsigned short* __restrict__ out,
    int R, int C)
{
    __shared__ float tile[32][33];
    int rb = blockIdx.x * 32, cb = blockIdx.y * 32;
    int tx = threadIdx.x & 31, ty = threadIdx.x >> 5;   // 32 x 8
    #pragma unroll
    for (int d = 0; d < 32; d += 8)
        tile[ty + d][tx] = in[(size_t)(rb + ty + d) * C + cb + tx];
    __syncthreads();
    #pragma unroll
    for (int d = 0; d < 32; d += 8)
        out[(size_t)(cb + ty + d) * R + rb + tx] = f2bf(tile[tx][ty + d]);
}

// ---------------------------------------------------------------------------
// K1: compacted gather + LayerNorm. One wave per valid event j.
// ---------------------------------------------------------------------------
__global__ __launch_bounds__(256) void embed_ln_kernel(
    const int* __restrict__ tok,  const int* __restrict__ ptok,
    const int* __restrict__ atok, const int* __restrict__ actok,
    const int* __restrict__ tgap, const int* __restrict__ gid,
    const float* __restrict__ ttab, const float* __restrict__ titab,
    const float* __restrict__ gtab, const float* __restrict__ gamma,
    const float* __restrict__ beta, const int* __restrict__ row_id,
    const int* __restrict__ Vdev, unsigned short* __restrict__ xln)
{
    int j = blockIdx.x * 4 + (threadIdx.x >> 6);
    if (j >= *Vdev) return;
    int l = threadIdx.x & 63;
    int rid = row_id[j];
    int i0 = tok[rid], i1 = ptok[rid], i2 = atok[rid], i3 = actok[rid];
    int i4 = tgap[rid]; i4 = i4 < 0 ? 0 : (i4 > TGB_ ? TGB_ : i4);
    int i5 = gid[rid];
    f32x4 v[6];
    v[0] = *(const f32x4*)(ttab  + (size_t)i0 * H_ + l * 4);
    v[1] = *(const f32x4*)(ttab  + (size_t)i1 * H_ + l * 4);
    v[2] = *(const f32x4*)(ttab  + (size_t)i2 * H_ + l * 4);
    v[3] = *(const f32x4*)(ttab  + (size_t)i3 * H_ + l * 4);
    v[4] = *(const f32x4*)(titab + (size_t)i4 * H_ + l * 4);
    v[5] = *(const f32x4*)(gtab  + (size_t)i5 * H_ + l * 4);
    float s = 0.0f, sq = 0.0f;
    #pragma unroll
    for (int k = 0; k < 6; ++k)
        #pragma unroll
        for (int c = 0; c < 4; ++c) { float f = v[k][c]; s += f; sq += f * f; }
    #pragma unroll
    for (int off = 32; off > 0; off >>= 1) {
        s  += __shfl_xor(s,  off);
        sq += __shfl_xor(sq, off);
    }
    float mean = s * (1.0f / 1536.0f);
    float var  = sq * (1.0f / 1536.0f) - mean * mean;
    float rstd = rsqrtf(var + 1e-5f);
    unsigned short* orow = xln + (size_t)j * SIXH;
    #pragma unroll
    for (int k = 0; k < 6; ++k) {
        f32x4 g = *(const f32x4*)(gamma + k * H_ + l * 4);
        f32x4 b = *(const f32x4*)(beta  + k * H_ + l * 4);
        u16x4 o;
        #pragma unroll
        for (int c = 0; c < 4; ++c)
            o[c] = f2bf((v[k][c] - mean) * rstd * g[c] + b[c]);
        *(u16x4*)(orow + k * H_ + l * 4) = o;
    }
}

// ---------------------------------------------------------------------------
// K2a: GEMM1 = r3-verified ring-of-3 deep pipeline, BM=256 x BN=128, BK=64,
// 512 thr = 8 waves (4m x 2n), counted s_waitcnt vmcnt(6), 144 KiB LDS.
// Blocks < nact: gemm tiles (m204 bijective XCD swizzle). Blocks >= nact:
// FILL role (zeros / sep slots / mask plane) -- depends only on scan,
// writes disjoint from GEMM2's event slots, rides free in gemm's tail
// (gemm is compute-bound: 17% HBM). silu epilogue -> bf16 C.
// ---------------------------------------------------------------------------
template<int N, int K, int NTN>
__global__ __launch_bounds__(512, 2) void gemm8_kernel(
    const unsigned short* __restrict__ A,
    const unsigned short* __restrict__ Bt,
    const float* __restrict__ bias,
    unsigned short* __restrict__ C,
    const int* __restrict__ Vdev,
    const int* __restrict__ idx_map,
    const int* __restrict__ shiftb,
    const float* __restrict__ ptab,
    const float* __restrict__ sep,
    float* __restrict__ outF)
{
    constexpr int NT = K / 64;                // K-tiles
    constexpr int ASLOT = 256 * 64;
    constexpr int BSLOT = 128 * 64;
    extern __shared__ __align__(16) unsigned short lds[];
    unsigned short* sA = lds;
    unsigned short* sB = lds + 3 * ASLOT;

    const int V = *Vdev;
    const int nact = ((V + 255) >> 8) * NTN;
    const int bid = blockIdx.x;
    int t = threadIdx.x;

    if (bid >= nact) {
        // ---- FILL role: zeros (s<shift), sep slots, mask plane ----
        const int nf = (int)gridDim.x - nact;      // >= 512 always
        const int w8 = t >> 6;                     // 8 waves -> 8 slots/iter
        const int hh = (t & 63) * 4;
        for (int u = (bid - nact) * 8 + w8; u < B_ * S_; u += nf * 8) {
            int b = u / S_;
            int s = u - b * S_;
            int shift = shiftb[b];
            float* orow = outF + ((size_t)b * S_ + s) * H_;
            if (s < shift) {
                *(f32x4*)(orow + hh) = (f32x4)0.0f;
            } else {
                int idx = idx_map[b * S_ + s];
                if (idx == -2) {
                    f32x4 pv = *(const f32x4*)(ptab + (size_t)s * H_ + hh);
                    f32x4 sv = *(const f32x4*)(sep + hh);
                    *(f32x4*)(orow + hh) = pv + sv;
                }
            }
            if ((t & 63) == 0)
                outF[(size_t)B_ * S_ * H_ + (size_t)b * S_ + s] = (s >= shift) ? 1.0f : 0.0f;
        }
        return;
    }

    const int qd = nact >> 3, rd = nact & 7, x = bid & 7, o = bid >> 3;
    const int wid = (x < rd ? x * (qd + 1) : rd * (qd + 1) + (x - rd) * qd) + o;
    const int m0 = (wid / NTN) * 256;
    const int n0 = (wid % NTN) * 128;

    int w = t >> 6, l = t & 63;
    int srow = t >> 3;
    int scg  = (t & 7) ^ (srow & 7);
    const unsigned short* Ag = A  + (size_t)(m0 + srow) * K + scg * 8;
    const unsigned short* Bg = Bt + (size_t)(n0 + srow) * K + scg * 8;
    unsigned short* stA = sA + w * 512;
    unsigned short* stB = sB + w * 512;

    int r16 = l & 15, q = l >> 4;
    int wm = w >> 1, wn = w & 1;             // 4m x 2n
    int xr = r16 & 7;
    const int aoff = (wm * 64 + r16) * 64;
    const int boff = (wn * 64 + r16) * 64;
    const int c0 = ((0 + q) ^ xr) * 8;
    const int c1 = ((4 + q) ^ xr) * 8;

    f32x4 acc[4][4];
    #pragma unroll
    for (int i = 0; i < 4; ++i)
        #pragma unroll
        for (int j = 0; j < 4; ++j) acc[i][j] = (f32x4)0.0f;

    // prologue: kt=0 -> slot0, kt=1 -> slot1
    #pragma unroll
    for (int j = 0; j < 4; ++j) gload_lds16(Ag + (size_t)j * 64 * K, stA + j * 4096);
    #pragma unroll
    for (int j = 0; j < 2; ++j) gload_lds16(Bg + (size_t)j * 64 * K, stB + j * 4096);
    #pragma unroll
    for (int j = 0; j < 4; ++j) gload_lds16(Ag + (size_t)j * 64 * K + 64, stA + ASLOT + j * 4096);
    #pragma unroll
    for (int j = 0; j < 2; ++j) gload_lds16(Bg + (size_t)j * 64 * K + 64, stB + BSLOT + j * 4096);
    asm volatile("s_waitcnt vmcnt(6)\ns_barrier" ::: "memory");

    int s = 0;
    for (int kt = 0; kt < NT; ++kt) {
        const unsigned short* sAs = sA + s * ASLOT;
        const unsigned short* sBs = sB + s * BSLOT;
        int spf = s + 2; if (spf >= 3) spf -= 3;
        const size_t gofs = (size_t)(kt + 2) * 64;
        unsigned short* pA = stA + spf * ASLOT;
        unsigned short* pB = stB + spf * BSLOT;

        bf16x8 af[4][2];
        #pragma unroll
        for (int mi = 0; mi < 4; ++mi) {
            af[mi][0] = *(const bf16x8*)(sAs + aoff + mi * 1024 + c0);
            af[mi][1] = *(const bf16x8*)(sAs + aoff + mi * 1024 + c1);
        }
        #pragma unroll
        for (int ni = 0; ni < 4; ++ni) {
            bf16x8 b0 = *(const bf16x8*)(sBs + boff + ni * 1024 + c0);
            bf16x8 b1 = *(const bf16x8*)(sBs + boff + ni * 1024 + c1);
            if (kt + 2 < NT) {
                if (ni == 0) {
                    gload_lds16(Ag + gofs,                    pA);
                    gload_lds16(Ag + (size_t) 64 * K + gofs,  pA + 4096);
                } else if (ni == 1) {
                    gload_lds16(Ag + (size_t)128 * K + gofs,  pA + 8192);
                    gload_lds16(Ag + (size_t)192 * K + gofs,  pA + 12288);
                } else if (ni == 2) {
                    gload_lds16(Bg + gofs,                    pB);
                } else {
                    gload_lds16(Bg + (size_t) 64 * K + gofs,  pB + 4096);
                }
            }
            __builtin_amdgcn_s_setprio(1);
            #pragma unroll
            for (int mi = 0; mi < 4; ++mi) {
                acc[mi][ni] = __builtin_amdgcn_mfma_f32_16x16x32_bf16(af[mi][0], b0, acc[mi][ni], 0, 0, 0);
                acc[mi][ni] = __builtin_amdgcn_mfma_f32_16x16x32_bf16(af[mi][1], b1, acc[mi][ni], 0, 0, 0);
            }
            __builtin_amdgcn_s_setprio(0);
        }
        if (kt + 2 < NT)      asm volatile("s_waitcnt vmcnt(6)\ns_barrier" ::: "memory");
        else if (kt + 1 < NT) asm volatile("s_waitcnt vmcnt(0)\ns_barrier" ::: "memory");
        s = (s == 2) ? 0 : s + 1;
    }

    // silu epilogue -> bf16 C
    #pragma unroll
    for (int mi = 0; mi < 4; ++mi) {
        #pragma unroll
        for (int ni = 0; ni < 4; ++ni) {
            int col = n0 + wn * 64 + ni * 16 + r16;
            float bv = bias[col];
            #pragma unroll
            for (int j = 0; j < 4; ++j) {
                int row = m0 + wm * 64 + mi * 16 + q * 4 + j;
                float v = acc[mi][ni][j] + bv;
                v = v / (1.0f + __expf(-v));   // silu
                C[(size_t)row * N + col] = f2bf(v);
            }
        }
    }
}

// ---------------------------------------------------------------------------
// K2b: GEMM2 = 8-phase 128x128 (r10 inner loop verbatim; 0 conflicts),
// fused scatter epilogue -> out f32. Grid 1024, XCD-preserving stride.
// ---------------------------------------------------------------------------
template<int K, int NTN>
__global__ __launch_bounds__(256, 2) void gemm128s_kernel(
    const unsigned short* __restrict__ A,
    const unsigned short* __restrict__ Bt,
    const float* __restrict__ bias,
    const int* __restrict__ outslot,
    const int* __restrict__ posC,
    const float* __restrict__ ptab,
    float* __restrict__ outF,
    const int* __restrict__ Vdev)
{
    constexpr int NT = K / 64;        // K-tiles
    constexpr int IT = NT / 2;        // 2 K-tiles per iteration
    extern __shared__ __align__(16) unsigned short lds[];   // 32768 shorts

    const int V = *Vdev;
    const int nact = ((V + 127) >> 7) * NTN;
    const int q = nact >> 3, r = nact & 7;

    const int t = threadIdx.x;
    const int w = t >> 6, l = t & 63;
    const int wm = w >> 1, wn = w & 1;
    const int r16 = l & 15, ql = l >> 4;
    const int sg = (t & 3) ^ ((t >> 3) & 3);
    unsigned short* ldsb = lds + w * 512;              // wave-uniform dest base
    const int fr = (ql ^ ((r16 >> 1) & 3)) * 8;

    const unsigned short* la0 = lds + (wm * 64 + r16) * 32 + fr;
    const unsigned short* la1 = la0 + 16384;
    const unsigned short* lb0 = lds + 8192 + (wn * 64 + r16) * 32 + fr;
    const unsigned short* lb1 = lb0 + 16384;

    for (int bidv = blockIdx.x; bidv < nact; bidv += (int)gridDim.x) {
        const int x = bidv & 7, o = bidv >> 3;
        const int wid = (x < r ? x * (q + 1) : r * (q + 1) + (x - r) * q) + o;
        const int mt  = wid / NTN;
        const int m0  = mt * 128;
        const int n0  = (wid - mt * NTN) * 128;

        const unsigned short* As0 = A  + (size_t)(m0 + (t >> 2)) * K + sg * 8;
        const unsigned short* As1 = As0 + (size_t)64 * K;
        const unsigned short* Bs0 = Bt + (size_t)(n0 + (t >> 2)) * K + sg * 8;
        const unsigned short* Bs1 = Bs0 + (size_t)64 * K;

        f32x4 acc[4][4];
        #pragma unroll
        for (int i = 0; i < 4; ++i)
            #pragma unroll
            for (int j = 0; j < 4; ++j) acc[i][j] = (f32x4)0.0f;

        auto ST2 = [&](const unsigned short* s0, const unsigned short* s1,
                       int dofs, int gofs) {
            gload_lds16(s0 + gofs, ldsb + dofs);
            gload_lds16(s1 + gofs, ldsb + dofs + 2048);
        };

        if (bidv != (int)blockIdx.x) __syncthreads();   // LDS WAR guard

        ST2(As0, As1, 0,     0);
        ST2(Bs0, Bs1, 8192,  0);
        ST2(As0, As1, 4096,  32);
        ST2(Bs0, Bs1, 12288, 32);
        ST2(As0, As1, 16384, 64);
        ST2(Bs0, Bs1, 24576, 64);
        asm volatile("s_waitcnt vmcnt(4)\ns_barrier" ::: "memory");

        bf16x8 bq[4];

        auto phase = [&](auto pc, bool last) {
            constexpr int P   = decltype(pc)::v;
            constexpr int BUF = P >> 2;
            constexpr int KK  = (P & 3) >> 1;
            constexpr int MH  = P & 1;
            const unsigned short* ab = (BUF ? la1 : la0) + KK * 4096 + MH * 1024;
            bf16x8 aq[2];
            if constexpr (MH == 0) {
                const unsigned short* bb = (BUF ? lb1 : lb0) + KK * 4096;
                bq[0] = *(const bf16x8*)(bb);
                bq[1] = *(const bf16x8*)(bb + 512);
                bq[2] = *(const bf16x8*)(bb + 1024);
                bq[3] = *(const bf16x8*)(bb + 1536);
            }
            aq[0] = *(const bf16x8*)(ab);
            aq[1] = *(const bf16x8*)(ab + 512);
            if constexpr (P == 0)      {            ST2(As0, As1, 20480, 96);  }
            else if constexpr (P == 1) {            ST2(Bs0, Bs1, 28672, 96);  }
            else if constexpr (P == 2) { if (!last) ST2(As0, As1, 0,     128); }
            else if constexpr (P == 3) { if (!last) ST2(Bs0, Bs1, 8192,  128); }
            else if constexpr (P == 4) { if (!last) ST2(As0, As1, 4096,  160); }
            else if constexpr (P == 5) { if (!last) ST2(Bs0, Bs1, 12288, 160); }
            else if constexpr (P == 6) { if (!last) ST2(As0, As1, 16384, 192); }
            else                       { if (!last) ST2(Bs0, Bs1, 24576, 192); }
            asm volatile("s_barrier" ::: "memory");
            __builtin_amdgcn_s_setprio(1);
            #pragma unroll
            for (int mm = 0; mm < 2; ++mm)
                #pragma unroll
                for (int nn = 0; nn < 4; ++nn)
                    acc[MH * 2 + mm][nn] = __builtin_amdgcn_mfma_f32_16x16x32_bf16(
                        aq[mm], bq[nn], acc[MH * 2 + mm][nn], 0, 0, 0);
            __builtin_amdgcn_s_setprio(0);
            if constexpr (P == 3) {
                if (last) asm volatile("s_waitcnt vmcnt(0)\ns_barrier" ::: "memory");
                else      asm volatile("s_waitcnt vmcnt(4)\ns_barrier" ::: "memory");
            } else if constexpr (P == 7) {
                if (!last) asm volatile("s_waitcnt vmcnt(4)\ns_barrier" ::: "memory");
            } else {
                asm volatile("s_barrier" ::: "memory");
            }
        };

        for (int it = 0; it < IT; ++it) {
            const bool last = (it == IT - 1);
            phase(IC<0>{}, last);
            phase(IC<1>{}, last);
            phase(IC<2>{}, last);
            phase(IC<3>{}, last);
            phase(IC<4>{}, last);
            phase(IC<5>{}, last);
            phase(IC<6>{}, last);
            phase(IC<7>{}, last);
            As0 += 128; As1 += 128; Bs0 += 128; Bs1 += 128;
        }

        // fused scatter: compact row -> out slot, + bias + pos_table
        #pragma unroll
        for (int mi = 0; mi < 4; ++mi) {
            #pragma unroll
            for (int j = 0; j < 4; ++j) {
                int row = m0 + wm * 64 + mi * 16 + ql * 4 + j;
                int slot = outslot[row];
                if (slot >= 0) {
                    float* orow = outF + (size_t)slot * H_;
                    const float* prow = ptab + (size_t)posC[row] * H_;
                    #pragma unroll
                    for (int ni = 0; ni < 4; ++ni) {
                        int col = n0 + wn * 64 + ni * 16 + r16;
                        orow[col] = acc[mi][ni][j] + bias[col] + prow[col];
                    }
                }
            }
        }
    }
}

// ---------------------------------------------------------------------------
// K3: per-batch boundary + cumsum + inverse map + compact maps.
// ---------------------------------------------------------------------------
__global__ __launch_bounds__(512) void scan_scatter_kernel(
    const int* __restrict__ gid, const int* __restrict__ lengths,
    int* __restrict__ idx_map, int* __restrict__ shiftb,
    int* __restrict__ row_id, int* __restrict__ outslot,
    int* __restrict__ posC, int* __restrict__ Vdev)
{
    int b = blockIdx.x, i = threadIdx.x;
    __shared__ int slen[128];
    __shared__ int sres[2];
    if (i < 128) slen[i] = lengths[i];
    __syncthreads();
    if (i < 64) {
        int vpart = (i < b ? slen[i] : 0) + (i + 64 < b ? slen[i + 64] : 0);
        int vall  = slen[i] + slen[i + 64];
        #pragma unroll
        for (int off = 32; off > 0; off >>= 1) {
            vpart += __shfl_xor(vpart, off);
            vall  += __shfl_xor(vall,  off);
        }
        if (i == 0) { sres[0] = vpart; sres[1] = vall; }
    }
    int len = lengths[b];
    int g  = gid[b * L_ + i];
    int gn = (i < L_ - 1) ? gid[b * L_ + i + 1] : g;
    int bnd = (i < len - 1 && g != gn) ? 1 : 0;
    __shared__ int sc[512];
    sc[i] = bnd;
    __syncthreads();
    for (int off = 1; off < 512; off <<= 1) {
        int v = (i >= off) ? sc[i - off] : 0;
        __syncthreads();
        sc[i] += v;
        __syncthreads();
    }
    int incl  = sc[i];
    int total = sc[511];
    int ex = incl - bnd;
    int M = len + total;
    int shift = S_ - M;          // always >= 0
    int pb = sres[0], V = sres[1];
    for (int s = i; s < S_; s += 512) idx_map[b * S_ + s] = -1;
    __syncthreads();
    if (i < len) {
        int p = shift + i + ex;
        idx_map[b * S_ + p] = i;
        if (bnd) idx_map[b * S_ + p + 1] = -2;
        int j = pb + i;
        row_id[j]  = b * L_ + i;
        outslot[j] = b * S_ + p;
        posC[j]    = p;
    }
    if (i == 0) shiftb[b] = shift;
    if (b == B_ - 1) {
        if (i == 0) *Vdev = V;
        if (i < 256) outslot[V + i] = -1;
    }
}

// ---------------------------------------------------------------------------
extern "C" void kernel_launch(void* const* d_in, const int* in_sizes, int n_in,
                              void* d_out, int out_size, void* d_ws, size_t ws_size,
                              hipStream_t stream)
{
    const int*   tok   = (const int*)d_in[0];
    const int*   ptok  = (const int*)d_in[1];
    const int*   atok  = (const int*)d_in[2];
    const int*   actok = (const int*)d_in[3];
    const int*   tgap  = (const int*)d_in[4];
    const int*   gid   = (const int*)d_in[5];
    const int*   lens  = (const int*)d_in[6];
    const float* ttab  = (const float*)d_in[7];
    const float* titab = (const float*)d_in[8];
    const float* gtab  = (const float*)d_in[9];
    const float* post  = (const float*)d_in[10];
    const float* sep   = (const float*)d_in[11];
    const float* gamma = (const float*)d_in[12];
    const float* beta  = (const float*)d_in[13];
    const float* W1    = (const float*)d_in[14];
    const float* b1    = (const float*)d_in[15];
    const float* W2    = (const float*)d_in[16];
    const float* b2    = (const float*)d_in[17];

    unsigned short* xln  = (unsigned short*)d_ws;                 // BL*1536 bf16
    unsigned short* hbuf = xln  + (size_t)BL_ * SIXH;             // BL*1024 bf16
    unsigned short* W1T  = hbuf + (size_t)BL_ * FOURH;            // 1024*1536 bf16
    unsigned short* W2T  = W1T  + (size_t)FOURH * SIXH;           // 256*1024 bf16
    int* idx_map = (int*)(W2T + (size_t)H_ * FOURH);              // B*S int
    int* shiftb  = idx_map + B_ * S_;                             // B
    int* Vdev    = shiftb + B_;                                   // 1 (+pad)
    int* row_id  = Vdev + 4;                                      // BL
    int* outslot = row_id + BL_;                                  // BL+256
    int* posC    = outslot + BL_ + 256;                           // BL
    float* out   = (float*)d_out;

    constexpr int LDS1 = 3 * (256 * 64 + 128 * 64) * 2;           // 147456
    constexpr int LDS2 = 2 * 16384 * 2;                           // 65536
    (void)hipFuncSetAttribute((const void*)&gemm8_kernel<FOURH, SIXH, 8>,
                              hipFuncAttributeMaxDynamicSharedMemorySize, LDS1);
    (void)hipFuncSetAttribute((const void*)&gemm128s_kernel<FOURH, 2>,
                              hipFuncAttributeMaxDynamicSharedMemorySize, LDS2);

    // weight transposes (independent)
    transpose_bf16_kernel<<<dim3(SIXH / 32, FOURH / 32), 256, 0, stream>>>(W1, W1T, SIXH, FOURH);
    transpose_bf16_kernel<<<dim3(FOURH / 32, H_ / 32),   256, 0, stream>>>(W2, W2T, FOURH, H_);

    // scan + prefix + compact maps + V + pad
    scan_scatter_kernel<<<B_, 512, 0, stream>>>(gid, lens, idx_map, shiftb,
                                                row_id, outslot, posC, Vdev);

    // compacted embed + layernorm
    embed_ln_kernel<<<BL_ / 4, 256, 0, stream>>>(tok, ptok, atok, actok, tgap, gid,
                                                 ttab, titab, gtab, gamma, beta,
                                                 row_id, Vdev, xln);

    // GEMM1 (ring-3 deep pipeline) + FILL role in blocks >= nact
    gemm8_kernel<FOURH, SIXH, 8><<<2560, 512, LDS1, stream>>>(
        xln, W1T, b1, hbuf, Vdev, idx_map, shiftb, post, sep, out);
    // GEMM2: 128^2 8-phase + fused scatter (grid 1024, XCD-preserving stride)
    gemm128s_kernel<FOURH, 2><<<1024, 256, LDS2, stream>>>(
        hbuf, W2T, b2, outslot, posC, post, out, Vdev);
}